// Round 1
// baseline (247.162 us; speedup 1.0000x reference)
//
#include <hip/hip_runtime.h>
#include <cmath>

#define NPTS 262144
#define NLVL 16
#define NDENSE 5
#define NHASH 11
#define HASH_MASK 0x7FFFFu
#define P2 2654435761u
#define P3 805459861u

typedef float v2f __attribute__((ext_vector_type(2)));
typedef float v4f __attribute__((ext_vector_type(4)));

struct MetaD { float scale[NDENSE]; unsigned off[NDENSE]; unsigned res[NDENSE]; };
struct MetaH { float scale[NHASH]; unsigned off[NHASH]; };

struct Pt { float x, y, z; };
struct Prep { unsigned idx[8]; float fx, fy, fz; };

__device__ __forceinline__ Pt load_pt(const float* __restrict__ means, int p) {
    Pt q;
    q.x = (__builtin_nontemporal_load(means + 3 * p + 0) + 1.0f) * 0.5f;
    q.y = (__builtin_nontemporal_load(means + 3 * p + 1) + 1.0f) * 0.5f;
    q.z = (__builtin_nontemporal_load(means + 3 * p + 2) + 1.0f) * 0.5f;
    return q;
}

// dense (linear-indexed) index prep — off folded into idx
__device__ __forceinline__ Prep dprep(Pt q, float s, unsigned r, unsigned off) {
    const float px = q.x * s, py = q.y * s, pz = q.z * s;
    const float gx = floorf(px), gy = floorf(py), gz = floorf(pz);
    Prep d;
    d.fx = px - gx; d.fy = py - gy; d.fz = pz - gz;
    const unsigned dy = r, dz = r * r;
    const unsigned base = (unsigned)gx + (unsigned)gy * dy + (unsigned)gz * dz + off;
    d.idx[0] = base;           d.idx[1] = base + 1;
    d.idx[2] = base + dy;      d.idx[3] = base + dy + 1;
    d.idx[4] = base + dz;      d.idx[5] = base + dz + 1;
    d.idx[6] = base + dz + dy; d.idx[7] = base + dz + dy + 1;
    return d;
}

// hash index prep (hsize = 2^19) — off folded into idx
__device__ __forceinline__ Prep hprep(Pt q, float s, unsigned off) {
    const float px = q.x * s, py = q.y * s, pz = q.z * s;
    const float gx = floorf(px), gy = floorf(py), gz = floorf(pz);
    Prep d;
    d.fx = px - gx; d.fy = py - gy; d.fz = pz - gz;
    const unsigned ix = (unsigned)gx, iy = (unsigned)gy, iz = (unsigned)gz;
    const unsigned hy0 = iy * P2, hy1 = hy0 + P2;
    const unsigned hz0 = iz * P3, hz1 = hz0 + P3;
    const unsigned h0 = hy0 ^ hz0, h1 = hy1 ^ hz0, h2 = hy0 ^ hz1, h3 = hy1 ^ hz1;
    d.idx[0] = ((ix ^ h0) & HASH_MASK) + off; d.idx[1] = (((ix + 1u) ^ h0) & HASH_MASK) + off;
    d.idx[2] = ((ix ^ h1) & HASH_MASK) + off; d.idx[3] = (((ix + 1u) ^ h1) & HASH_MASK) + off;
    d.idx[4] = ((ix ^ h2) & HASH_MASK) + off; d.idx[5] = (((ix + 1u) ^ h2) & HASH_MASK) + off;
    d.idx[6] = ((ix ^ h3) & HASH_MASK) + off; d.idx[7] = (((ix + 1u) ^ h3) & HASH_MASK) + off;
    return d;
}

// weights: w00=wz0*wy0 pairs f[0],f[1]; w01=wz0*fy -> f[2],f[3];
// w10=fz*wy0 -> f[4],f[5]; w11=fz*fy -> f[6],f[7]  (matches ref corner order)
__device__ __forceinline__ v2f trilerp(const v2f* f, float fx, float fy, float fz) {
    const float wx0 = 1.0f - fx, wy0 = 1.0f - fy, wz0 = 1.0f - fz;
    const float w00 = wz0 * wy0, w01 = wz0 * fy, w10 = fz * wy0, w11 = fz * fy;
    return w00 * (wx0 * f[0] + fx * f[1]) + w01 * (wx0 * f[2] + fx * f[3])
         + w10 * (wx0 * f[4] + fx * f[5]) + w11 * (wx0 * f[6] + fx * f[7]);
}

// ---------------- dense levels 0..4: 2 points/thread, all 16 gathers hoisted ----------------
__global__ __launch_bounds__(256) void enc_dense(
    const float* __restrict__ means, const float* __restrict__ emb,
    v2f* __restrict__ dst, int lvl_major, MetaD meta)
{
    const int l = blockIdx.y;                    // wave-uniform level
    const int p0 = blockIdx.x * 512 + threadIdx.x;
    const float s = meta.scale[l];
    const unsigned off = meta.off[l];
    const unsigned r = meta.res[l];
    const v2f* __restrict__ emb2 = (const v2f*)emb;

    const Prep A = dprep(load_pt(means, p0), s, r, off);
    v2f fa[8];
#pragma unroll
    for (int k = 0; k < 8; ++k) fa[k] = emb2[A.idx[k]];
    const Prep B = dprep(load_pt(means, p0 + 256), s, r, off);
    v2f fb[8];
#pragma unroll
    for (int k = 0; k < 8; ++k) fb[k] = emb2[B.idx[k]];

    const v2f ra = trilerp(fa, A.fx, A.fy, A.fz);
    const size_t diA = lvl_major ? ((size_t)l * NPTS + p0) : ((size_t)p0 * NLVL + l);
    __builtin_nontemporal_store(ra, &dst[diA]);
    const v2f rb = trilerp(fb, B.fx, B.fy, B.fz);
    const size_t diB = lvl_major ? ((size_t)l * NPTS + p0 + 256) : ((size_t)(p0 + 256) * NLVL + l);
    __builtin_nontemporal_store(rb, &dst[diB]);
}

// ---------------- hash levels 5..15, XCD-affine, balanced 704 jobs/XCD ----------------
// slots < 512: own level il = xcd, chunk = slot (own table resident in this XCD's L2).
// slots >= 512: 192 shared-level chunks per XCD from the 3*512 pool of levels 8..10.
__global__ __launch_bounds__(256) void enc_hash(
    const float* __restrict__ means, const float* __restrict__ emb,
    v2f* __restrict__ dst, int lvl_major, MetaH meta)
{
    const unsigned b = blockIdx.x;
    const unsigned xcd = b & 7u, slot = b >> 3;
    unsigned il, chunk;
    if (slot < 512u) { il = xcd; chunk = slot; }
    else {
        const unsigned g = xcd * 192u + (slot - 512u);   // 0..1535
        il = 8u + (g >> 9);
        chunk = g & 511u;
    }
    const float s = meta.scale[il];
    const unsigned off = meta.off[il];
    const unsigned lvl = il + NDENSE;
    const int p0 = (int)(chunk * 512u + threadIdx.x);
    const v2f* __restrict__ emb2 = (const v2f*)emb;

    const Prep A = hprep(load_pt(means, p0), s, off);
    v2f fa[8];
#pragma unroll
    for (int k = 0; k < 8; ++k) fa[k] = emb2[A.idx[k]];
    const Prep B = hprep(load_pt(means, p0 + 256), s, off);
    v2f fb[8];
#pragma unroll
    for (int k = 0; k < 8; ++k) fb[k] = emb2[B.idx[k]];

    const v2f ra = trilerp(fa, A.fx, A.fy, A.fz);
    const size_t diA = lvl_major ? ((size_t)lvl * NPTS + p0) : ((size_t)p0 * NLVL + lvl);
    __builtin_nontemporal_store(ra, &dst[diA]);
    const v2f rb = trilerp(fb, B.fx, B.fy, B.fz);
    const size_t diB = lvl_major ? ((size_t)lvl * NPTS + (p0 + 256)) : ((size_t)(p0 + 256) * NLVL + lvl);
    __builtin_nontemporal_store(rb, &dst[diB]);
}

// ---------------- transpose ws[level][point] -> out[point][level] ----------------
__global__ __launch_bounds__(256) void transpose_out(
    const v2f* __restrict__ ws, float* __restrict__ out)
{
    const int p = blockIdx.x * 256 + threadIdx.x;
    v4f o[8];
    v2f* o2 = (v2f*)o;
#pragma unroll
    for (int l = 0; l < NLVL; ++l)
        o2[l] = __builtin_nontemporal_load(&ws[(size_t)l * NPTS + p]);
    v4f* out4 = (v4f*)(out + (size_t)p * (2 * NLVL));
#pragma unroll
    for (int k = 0; k < 8; ++k)
        __builtin_nontemporal_store(o[k], &out4[k]);
}

extern "C" void kernel_launch(void* const* d_in, const int* in_sizes, int n_in,
                              void* d_out, int out_size, void* d_ws, size_t ws_size,
                              hipStream_t stream)
{
    const float* means = (const float*)d_in[0];
    const float* emb   = (const float*)d_in[1];
    float* out         = (float*)d_out;

    MetaD md;
    MetaH mh;
    const double lg = log2(1.38191288);
    unsigned off = 0;
    for (int l = 0; l < NLVL; ++l) {
        const double scale_d = pow(2.0, (double)l * lg) * 16.0 - 1.0;
        const unsigned res_enc = (unsigned)ceil(scale_d) + 1u;

        const double gres_d = ceil(16.0 * pow(1.38191288, (double)l));
        unsigned long long r3 = (unsigned long long)gres_d;
        r3 = r3 * r3 * r3;
        unsigned long long pl = r3 < (1ull << 19) ? r3 : (1ull << 19);
        pl = (pl + 7ull) / 8ull * 8ull;

        if (l < NDENSE) {
            md.scale[l] = (float)scale_d;
            md.off[l]   = off;
            md.res[l]   = res_enc;
        } else {
            mh.scale[l - NDENSE] = (float)scale_d;
            mh.off[l - NDENSE]   = off;
        }
        off += (unsigned)pl;
    }

    const size_t ws_needed = (size_t)NLVL * NPTS * sizeof(float) * 2;  // 32 MB
    const bool use_ws = ws_size >= ws_needed;
    v2f* dst = use_ws ? (v2f*)d_ws : (v2f*)out;
    const int lvl_major = use_ws ? 1 : 0;

    enc_dense<<<dim3(NPTS / 512, NDENSE, 1), 256, 0, stream>>>(means, emb, dst, lvl_major, md);
    enc_hash <<<dim3(8 * 704, 1, 1),          256, 0, stream>>>(means, emb, dst, lvl_major, mh);
    if (use_ws)
        transpose_out<<<NPTS / 256, 256, 0, stream>>>((const v2f*)d_ws, out);
}